// Round 1
// baseline (712.099 us; speedup 1.0000x reference)
//
#include <hip/hip_runtime.h>
#include <hip/hip_fp16.h>
#include <cstdint>

typedef _Float16 f16;
typedef __attribute__((ext_vector_type(8))) _Float16 f16x8;
typedef __attribute__((ext_vector_type(4))) _Float16 f16x4;
typedef __attribute__((ext_vector_type(4))) float f32x4;

typedef __attribute__((address_space(1))) void gvoid_t;
typedef __attribute__((address_space(3))) void lvoid_t;

// async global->LDS, 16B per lane. LDS dest must be wave-uniform base; HW adds lane*16.
__device__ __forceinline__ void async_copy16(void* lds, const void* g) {
  // AS1 pointers are numerically identical to flat, so integer cast is value-correct
  // (and strips const); LDS side uses a real addrspacecast.
  __builtin_amdgcn_global_load_lds((gvoid_t*)(uintptr_t)g, (lvoid_t*)lds, 16, 0, 0);
}

#define BT 128
#define BK 32

// C[z][m][n] = scale * sum_k A[z][m][k] * B[z][n][k] + bias[n]
// A: [M][lda] f16 (batch stride sA), B: [N][ldb] f16 (batch stride sB, "B^T" layout)
// C: f16 or f32 per OUT_F16, leading dim ldc, batch stride sC.
template<int OUT_F16>
__global__ __launch_bounds__(256)
void gemm_bt(const f16* __restrict__ A, int lda, long sA,
             const f16* __restrict__ B, int ldb, long sB,
             void* __restrict__ Cv, int ldc, long sC,
             const float* __restrict__ bias, float scale, int K)
{
  __shared__ f16 As[BT * BK];
  __shared__ f16 Bs[BT * BK];

  const int tid  = threadIdx.x;
  const int lane = tid & 63;
  const int wave = tid >> 6;
  const int wr = wave >> 1, wc = wave & 1;     // wave -> 64x64 quadrant
  const int l15 = lane & 15, lk = lane >> 4;   // MFMA fragment coords

  const long brow = (long)blockIdx.y * BT;
  const long bcol = (long)blockIdx.x * BT;
  const int z = blockIdx.z;
  const f16* Ab = A + (long)z * sA;
  const f16* Bb = B + (long)z * sB;

  // staging: 128x32 f16 tile = 8192B; 256 threads x 2 instrs x 16B
  const int e0 = tid * 8;        // linear element index of this thread's first 8 elems
  const int r0 = e0 >> 5;        // row 0..63
  const int c0 = e0 & 31;        // col 0/8/16/24

  f16* dstA0 = As + wave * 512;          // wave-uniform LDS bases (elements)
  f16* dstA1 = As + 2048 + wave * 512;
  f16* dstB0 = Bs + wave * 512;
  f16* dstB1 = Bs + 2048 + wave * 512;

  f32x4 acc[4][4] = {};

  for (int k0 = 0; k0 < K; k0 += BK) {
    async_copy16(dstA0, Ab + (brow + r0) * lda + k0 + c0);
    async_copy16(dstA1, Ab + (brow + r0 + 64) * lda + k0 + c0);
    async_copy16(dstB0, Bb + (bcol + r0) * ldb + k0 + c0);
    async_copy16(dstB1, Bb + (bcol + r0 + 64) * ldb + k0 + c0);
    __syncthreads();

    f16x8 af[4], bf[4];
#pragma unroll
    for (int m = 0; m < 4; ++m)
      af[m] = *reinterpret_cast<const f16x8*>(&As[(wr * 64 + m * 16 + l15) * BK + lk * 8]);
#pragma unroll
    for (int n = 0; n < 4; ++n)
      bf[n] = *reinterpret_cast<const f16x8*>(&Bs[(wc * 64 + n * 16 + l15) * BK + lk * 8]);
#pragma unroll
    for (int m = 0; m < 4; ++m)
#pragma unroll
      for (int n = 0; n < 4; ++n)
        acc[m][n] = __builtin_amdgcn_mfma_f32_16x16x32_f16(af[m], bf[n], acc[m][n], 0, 0, 0);
    __syncthreads();
  }

  // epilogue: C/D layout col = lane&15, row = (lane>>4)*4 + j  [m89-verified]
#pragma unroll
  for (int m = 0; m < 4; ++m) {
#pragma unroll
    for (int n = 0; n < 4; ++n) {
      const long col = bcol + wc * 64 + n * 16 + l15;
      const float bv = bias ? bias[col] : 0.0f;
#pragma unroll
      for (int j = 0; j < 4; ++j) {
        const long row = brow + wr * 64 + m * 16 + lk * 4 + j;
        const float v = acc[m][n][j] * scale + bv;
        if (OUT_F16)
          ((f16*)Cv)[(long)z * sC + row * ldc + col] = (f16)v;
        else
          ((float*)Cv)[(long)z * sC + row * ldc + col] = v;
      }
    }
  }
}

__global__ void cast_f32_f16(const float* __restrict__ in, f16* __restrict__ out, long n) {
  long i = ((long)blockIdx.x * blockDim.x + threadIdx.x) * 4;
  const long stride = (long)gridDim.x * blockDim.x * 4;
  for (; i < n; i += stride) {
    const float4 v = *reinterpret_cast<const float4*>(in + i);
    f16x4 h;
    h.x = (f16)v.x; h.y = (f16)v.y; h.z = (f16)v.z; h.w = (f16)v.w;
    *reinterpret_cast<f16x4*>(out + i) = h;
  }
}

// vt[b][h][s] = qkv[b*2048+s][4096+h]   (extract V and transpose, per batch)
__global__ __launch_bounds__(256)
void transpose_v(const f16* __restrict__ qkv, f16* __restrict__ vt) {
  __shared__ f16 t[32][33];
  const int b = blockIdx.z;
  const int s0 = blockIdx.y * 32, h0 = blockIdx.x * 32;
  const int tx = threadIdx.x, ty = threadIdx.y;  // 32 x 8
  const f16* src = qkv + (long)b * 2048 * 6144 + 4096;
  f16* dst = vt + (long)b * 2048 * 2048;
#pragma unroll
  for (int i = 0; i < 4; ++i)
    t[ty + i * 8][tx] = src[(long)(s0 + ty + i * 8) * 6144 + h0 + tx];
  __syncthreads();
#pragma unroll
  for (int i = 0; i < 4; ++i)
    dst[(long)(h0 + ty + i * 8) * 2048 + s0 + tx] = t[tx][ty + i * 8];
}

// one block per row of 2048 f32 scores; writes f16 probs in-place (row stride 4096 f16)
__global__ __launch_bounds__(256)
void softmax_rows(float* __restrict__ scores) {
  const long row = blockIdx.x;
  float* s = scores + row * 2048;
  const int tid = threadIdx.x;
  const int lane = tid & 63;
  const int wave = tid >> 6;

  const float4 a = *reinterpret_cast<const float4*>(s + tid * 8);
  const float4 b = *reinterpret_cast<const float4*>(s + tid * 8 + 4);
  float v[8] = {a.x, a.y, a.z, a.w, b.x, b.y, b.z, b.w};

  float mx = v[0];
#pragma unroll
  for (int j = 1; j < 8; ++j) mx = fmaxf(mx, v[j]);
#pragma unroll
  for (int off = 32; off >= 1; off >>= 1) mx = fmaxf(mx, __shfl_xor(mx, off));
  __shared__ float red[4];
  if (lane == 0) red[wave] = mx;
  __syncthreads();
  mx = fmaxf(fmaxf(red[0], red[1]), fmaxf(red[2], red[3]));

  float sum = 0.f;
#pragma unroll
  for (int j = 0; j < 8; ++j) { v[j] = __expf(v[j] - mx); sum += v[j]; }
#pragma unroll
  for (int off = 32; off >= 1; off >>= 1) sum += __shfl_xor(sum, off);
  __shared__ float red2[4];
  if (lane == 0) red2[wave] = sum;
  __syncthreads();
  const float inv = 1.0f / (red2[0] + red2[1] + red2[2] + red2[3]);

  f16* p = reinterpret_cast<f16*>(scores) + row * 4096 + tid * 8;
  f16x8 h;
#pragma unroll
  for (int j = 0; j < 8; ++j) h[j] = (f16)(v[j] * inv);
  *reinterpret_cast<f16x8*>(p) = h;
}

extern "C" void kernel_launch(void* const* d_in, const int* in_sizes, int n_in,
                              void* d_out, int out_size, void* d_ws, size_t ws_size,
                              hipStream_t stream) {
  const float* x     = (const float*)d_in[0];  // [4,2048,2048]
  const float* w_qkv = (const float*)d_in[1];  // [6144,2048]
  const float* b_qkv = (const float*)d_in[2];  // [6144]
  const float* w_out = (const float*)d_in[3];  // [2048,2048]
  const float* b_out = (const float*)d_in[4];  // [2048]
  float* out = (float*)d_out;                  // [4,2048,2048] f32

  char* ws = (char*)d_ws;
  f16*   Xh    = (f16*)(ws + 0);           //  33.5 MB  [8192][2048]
  f16*   Wqkvh = (f16*)(ws + 33554432L);   //  25.2 MB  [6144][2048]
  f16*   Wouth = (f16*)(ws + 58720256L);   //   8.4 MB  [2048][2048]
  f16*   QKV   = (f16*)(ws + 67108864L);   // 100.7 MB  [8192][6144]
  float* SC    = (float*)(ws + 167772160L);//  67.1 MB  [4][2048][2048] f32 (probs f16 in-place)
  f16*   VT    = (f16*)(ws + 234881024L);  //  33.5 MB  [4][2048][2048]
  f16*   CTX   = Xh;                       // reuse X region after gemm1

  const float inv_sqrt_h = 0.022097086912079608f;  // 1/sqrt(2048)

  cast_f32_f16<<<2048, 256, 0, stream>>>(x,     Xh,    16777216L);
  cast_f32_f16<<<2048, 256, 0, stream>>>(w_qkv, Wqkvh, 12582912L);
  cast_f32_f16<<<1024, 256, 0, stream>>>(w_out, Wouth, 4194304L);

  // qkv = x @ w_qkv^T + b_qkv   [8192 x 6144]
  gemm_bt<1><<<dim3(48, 64, 1), 256, 0, stream>>>(
      Xh, 2048, 0, Wqkvh, 2048, 0, QKV, 6144, 0, b_qkv, 1.0f, 2048);

  // scores = Q @ K^T / sqrt(H)  per batch  [2048 x 2048] f32
  gemm_bt<0><<<dim3(16, 16, 4), 256, 0, stream>>>(
      QKV, 6144, 2048L * 6144, QKV + 2048, 6144, 2048L * 6144,
      SC, 2048, 2048L * 2048, nullptr, inv_sqrt_h, 2048);

  transpose_v<<<dim3(64, 64, 4), dim3(32, 8), 0, stream>>>(QKV, VT);

  softmax_rows<<<8192, 256, 0, stream>>>(SC);

  // context = P @ V  per batch (probs f16 in-place in SC, row stride 4096)
  gemm_bt<1><<<dim3(16, 16, 4), 256, 0, stream>>>(
      (const f16*)SC, 4096, 2048L * 4096, VT, 2048, 2048L * 2048,
      CTX, 2048, 2048L * 2048, nullptr, 1.0f, 2048);

  // out = context @ w_out^T + b_out   [8192 x 2048] f32
  gemm_bt<0><<<dim3(16, 64, 1), 256, 0, stream>>>(
      CTX, 2048, 0, Wouth, 2048, 0, out, 2048, 0, b_out, 1.0f, 2048);
}

// Round 2
// 675.193 us; speedup vs baseline: 1.0547x; 1.0547x over previous
//
#include <hip/hip_runtime.h>
#include <cstdint>

typedef _Float16 f16;
typedef __attribute__((ext_vector_type(8))) _Float16 f16x8;
typedef __attribute__((ext_vector_type(4))) _Float16 f16x4;
typedef __attribute__((ext_vector_type(4))) float f32x4;

typedef __attribute__((address_space(1))) void gvoid_t;
typedef __attribute__((address_space(3))) void lvoid_t;

// async global->LDS, 16B per lane. LDS dest wave-uniform base; HW adds lane*16.
__device__ __forceinline__ void async_copy16(void* lds, const void* g) {
  __builtin_amdgcn_global_load_lds((gvoid_t*)(uintptr_t)g, (lvoid_t*)lds, 16, 0, 0);
}

#define BARRIER()  asm volatile("s_barrier" ::: "memory")
#define VMCNT4()   asm volatile("s_waitcnt vmcnt(4)" ::: "memory")
#define VMCNT0()   asm volatile("s_waitcnt vmcnt(0)" ::: "memory")

// 256x256 tile, BK=32, 8 waves (2M x 4N), 4-deep LDS ring, counted vmcnt.
// C[z][m][n] = scale * sum_k A[z][m][k]*B[z][n][k] + bias[n]
template<int OUT_F16>
__global__ __launch_bounds__(512, 2)
void gemm256(const f16* __restrict__ A, int lda, long sA,
             const f16* __restrict__ B, int ldb, long sB,
             void* __restrict__ Cv, int ldc, long sC,
             const float* __restrict__ bias, float scale, int K)
{
  __shared__ f16 SA[4][256 * 32];   // 4 x 16 KB
  __shared__ f16 SB[4][256 * 32];   // 4 x 16 KB  (total 128 KB)

  const int tid  = threadIdx.x;
  const int lane = tid & 63;
  const int wave = tid >> 6;        // 0..7
  const int wr = wave >> 2;         // 0..1 : M half (128 rows)
  const int wc = wave & 3;          // 0..3 : N quarter (64 cols)
  const int l15 = lane & 15, lk = lane >> 4;

  const long brow = (long)blockIdx.y * 256;
  const long bcol = (long)blockIdx.x * 256;
  const int z = blockIdx.z;
  const f16* Ab = A + (long)z * sA;
  const f16* Bb = B + (long)z * sB;

  // staging geometry: per 128-row half-tile, thread tid owns LDS slot
  // (row = tid>>2, col8 = tid&3); global source col is pre-swizzled so that
  // LDS[row][c] holds global col (c ^ ((row>>1)&3)).  (rule 21: linear dest,
  // inverse-swizzled source, swizzled read.)
  const int srow  = tid >> 2;                       // 0..127
  const int scol8 = (tid & 3) ^ ((tid >> 3) & 3);   // pre-swizzled col block
  const int sdst  = wave * 512;                     // wave-uniform elem offset in half

#define STAGE_A(sb, tt) {                                                        \
    async_copy16(&SA[sb][sdst],                                                  \
                 Ab + (brow + srow) * (long)lda + (long)(tt) * 32 + scol8 * 8);  \
    async_copy16(&SA[sb][4096 + sdst],                                           \
                 Ab + (brow + 128 + srow) * (long)lda + (long)(tt) * 32 + scol8 * 8); }
#define STAGE_B(sb, tt) {                                                        \
    async_copy16(&SB[sb][sdst],                                                  \
                 Bb + (bcol + srow) * (long)ldb + (long)(tt) * 32 + scol8 * 8);  \
    async_copy16(&SB[sb][4096 + sdst],                                           \
                 Bb + (bcol + 128 + srow) * (long)ldb + (long)(tt) * 32 + scol8 * 8); }

// swizzled ds_read of one 16-row fragment (f16x8 per lane)
#define RD_A(dst, buf, mm) { const int ra = wr * 128 + (mm) * 16 + l15;          \
    dst = *reinterpret_cast<const f16x8*>(&SA[buf][ra * 32 + ((lk ^ ((ra >> 1) & 3)) * 8)]); }
#define RD_B(dst, buf, nn) { const int rb = wc * 64 + (nn) * 16 + l15;           \
    dst = *reinterpret_cast<const f16x8*>(&SB[buf][rb * 32 + ((lk ^ ((rb >> 1) & 3)) * 8)]); }

  f32x4 acc[8][4] = {};
  const int NT = K >> 5;

  // prologue: stage tiles 0 and 1 (8 loads); wait tile 0 (leave tile 1 in flight)
  STAGE_A(0, 0); STAGE_B(0, 0);
  STAGE_A(1, 1); STAGE_B(1, 1);
  VMCNT4();
  BARRIER();

  for (int t = 0; t < NT; ++t) {
    const int buf = t & 3;
    const int sb  = (t + 2) & 3;
    const bool st = (t + 2) < NT;
    f16x8 af[4], bf[4];

    // ---- phase 0: stage A(t+2) | read A(m0..3)+B | 16 MFMA ----
    if (st) STAGE_A(sb, t + 2);
    RD_A(af[0], buf, 0); RD_A(af[1], buf, 1); RD_A(af[2], buf, 2); RD_A(af[3], buf, 3);
    RD_B(bf[0], buf, 0); RD_B(bf[1], buf, 1); RD_B(bf[2], buf, 2); RD_B(bf[3], buf, 3);
    BARRIER();
    __builtin_amdgcn_s_setprio(1);
#pragma unroll
    for (int m = 0; m < 4; ++m)
#pragma unroll
      for (int n = 0; n < 4; ++n)
        acc[m][n] = __builtin_amdgcn_mfma_f32_16x16x32_f16(af[m], bf[n], acc[m][n], 0, 0, 0);
    __builtin_amdgcn_s_setprio(0);
    BARRIER();

    // ---- phase 1: stage B(t+2) | read A(m4..7) | 16 MFMA ----
    if (st) STAGE_B(sb, t + 2);
    RD_A(af[0], buf, 4); RD_A(af[1], buf, 5); RD_A(af[2], buf, 6); RD_A(af[3], buf, 7);
    BARRIER();
    __builtin_amdgcn_s_setprio(1);
#pragma unroll
    for (int m = 0; m < 4; ++m)
#pragma unroll
      for (int n = 0; n < 4; ++n)
        acc[m + 4][n] = __builtin_amdgcn_mfma_f32_16x16x32_f16(af[m], bf[n], acc[m + 4][n], 0, 0, 0);
    __builtin_amdgcn_s_setprio(0);
    // end of tile: ensure tile t+1 fully landed; leave tile t+2 (4 loads) in flight
    if (st) { VMCNT4(); } else { VMCNT0(); }
    BARRIER();
  }

  // epilogue: C/D layout col = lane&15, row = (lane>>4)*4 + j
#pragma unroll
  for (int m = 0; m < 8; ++m) {
#pragma unroll
    for (int n = 0; n < 4; ++n) {
      const long col = bcol + wc * 64 + n * 16 + l15;
      const float bv = bias ? bias[col] : 0.0f;
#pragma unroll
      for (int j = 0; j < 4; ++j) {
        const long row = brow + wr * 128 + m * 16 + lk * 4 + j;
        const float v = acc[m][n][j] * scale + bv;
        if (OUT_F16)
          ((f16*)Cv)[(long)z * sC + row * ldc + col] = (f16)v;
        else
          ((float*)Cv)[(long)z * sC + row * ldc + col] = v;
      }
    }
  }
#undef STAGE_A
#undef STAGE_B
#undef RD_A
#undef RD_B
}

__global__ void cast_f32_f16(const float* __restrict__ in, f16* __restrict__ out, long n) {
  long i = ((long)blockIdx.x * blockDim.x + threadIdx.x) * 4;
  const long stride = (long)gridDim.x * blockDim.x * 4;
  for (; i < n; i += stride) {
    const float4 v = *reinterpret_cast<const float4*>(in + i);
    f16x4 h;
    h.x = (f16)v.x; h.y = (f16)v.y; h.z = (f16)v.z; h.w = (f16)v.w;
    *reinterpret_cast<f16x4*>(out + i) = h;
  }
}

// vt[b][h][s] = qkv[b*2048+s][4096+h]   (extract V and transpose, per batch)
__global__ __launch_bounds__(256)
void transpose_v(const f16* __restrict__ qkv, f16* __restrict__ vt) {
  __shared__ f16 t[32][33];
  const int b = blockIdx.z;
  const int s0 = blockIdx.y * 32, h0 = blockIdx.x * 32;
  const int tx = threadIdx.x, ty = threadIdx.y;  // 32 x 8
  const f16* src = qkv + (long)b * 2048 * 6144 + 4096;
  f16* dst = vt + (long)b * 2048 * 2048;
#pragma unroll
  for (int i = 0; i < 4; ++i)
    t[ty + i * 8][tx] = src[(long)(s0 + ty + i * 8) * 6144 + h0 + tx];
  __syncthreads();
#pragma unroll
  for (int i = 0; i < 4; ++i)
    dst[(long)(h0 + ty + i * 8) * 2048 + s0 + tx] = t[tx][ty + i * 8];
}

// one block per row of 2048 f32 scores; writes f16 probs in-place (row stride 4096 f16)
__global__ __launch_bounds__(256)
void softmax_rows(float* __restrict__ scores) {
  const long row = blockIdx.x;
  float* s = scores + row * 2048;
  const int tid = threadIdx.x;
  const int lane = tid & 63;
  const int wave = tid >> 6;

  const float4 a = *reinterpret_cast<const float4*>(s + tid * 8);
  const float4 b = *reinterpret_cast<const float4*>(s + tid * 8 + 4);
  float v[8] = {a.x, a.y, a.z, a.w, b.x, b.y, b.z, b.w};

  float mx = v[0];
#pragma unroll
  for (int j = 1; j < 8; ++j) mx = fmaxf(mx, v[j]);
#pragma unroll
  for (int off = 32; off >= 1; off >>= 1) mx = fmaxf(mx, __shfl_xor(mx, off));
  __shared__ float red[4];
  if (lane == 0) red[wave] = mx;
  __syncthreads();
  mx = fmaxf(fmaxf(red[0], red[1]), fmaxf(red[2], red[3]));

  float sum = 0.f;
#pragma unroll
  for (int j = 0; j < 8; ++j) { v[j] = __expf(v[j] - mx); sum += v[j]; }
#pragma unroll
  for (int off = 32; off >= 1; off >>= 1) sum += __shfl_xor(sum, off);
  __shared__ float red2[4];
  if (lane == 0) red2[wave] = sum;
  __syncthreads();
  const float inv = 1.0f / (red2[0] + red2[1] + red2[2] + red2[3]);

  f16* p = reinterpret_cast<f16*>(scores) + row * 4096 + tid * 8;
  f16x8 h;
#pragma unroll
  for (int j = 0; j < 8; ++j) h[j] = (f16)(v[j] * inv);
  *reinterpret_cast<f16x8*>(p) = h;
}

extern "C" void kernel_launch(void* const* d_in, const int* in_sizes, int n_in,
                              void* d_out, int out_size, void* d_ws, size_t ws_size,
                              hipStream_t stream) {
  const float* x     = (const float*)d_in[0];  // [4,2048,2048]
  const float* w_qkv = (const float*)d_in[1];  // [6144,2048]
  const float* b_qkv = (const float*)d_in[2];  // [6144]
  const float* w_out = (const float*)d_in[3];  // [2048,2048]
  const float* b_out = (const float*)d_in[4];  // [2048]
  float* out = (float*)d_out;                  // [4,2048,2048] f32

  char* ws = (char*)d_ws;
  f16*   Xh    = (f16*)(ws + 0);           //  33.5 MB  [8192][2048]
  f16*   Wqkvh = (f16*)(ws + 33554432L);   //  25.2 MB  [6144][2048]
  f16*   Wouth = (f16*)(ws + 58720256L);   //   8.4 MB  [2048][2048]
  f16*   QKV   = (f16*)(ws + 67108864L);   // 100.7 MB  [8192][6144]
  float* SC    = (float*)(ws + 167772160L);//  67.1 MB  [4][2048][2048] f32 (probs f16 in-place)
  f16*   VT    = (f16*)(ws + 234881024L);  //  33.5 MB  [4][2048][2048]
  f16*   CTX   = Xh;                       // reuse X region after gemm1

  const float inv_sqrt_h = 0.022097086912079608f;  // 1/sqrt(2048)

  cast_f32_f16<<<2048, 256, 0, stream>>>(x,     Xh,    16777216L);
  cast_f32_f16<<<2048, 256, 0, stream>>>(w_qkv, Wqkvh, 12582912L);
  cast_f32_f16<<<1024, 256, 0, stream>>>(w_out, Wouth, 4194304L);

  // qkv = x @ w_qkv^T + b_qkv   [8192 x 6144]
  gemm256<1><<<dim3(24, 32, 1), 512, 0, stream>>>(
      Xh, 2048, 0, Wqkvh, 2048, 0, QKV, 6144, 0, b_qkv, 1.0f, 2048);

  // scores = Q @ K^T / sqrt(H)  per batch  [2048 x 2048] f32
  gemm256<0><<<dim3(8, 8, 4), 512, 0, stream>>>(
      QKV, 6144, 2048L * 6144, QKV + 2048, 6144, 2048L * 6144,
      SC, 2048, 2048L * 2048, nullptr, inv_sqrt_h, 2048);

  transpose_v<<<dim3(64, 64, 4), dim3(32, 8), 0, stream>>>(QKV, VT);

  softmax_rows<<<8192, 256, 0, stream>>>(SC);

  // context = P @ V  per batch (probs f16 in-place in SC, row stride 4096)
  gemm256<1><<<dim3(8, 8, 4), 512, 0, stream>>>(
      (const f16*)SC, 4096, 2048L * 4096, VT, 2048, 2048L * 2048,
      CTX, 2048, 2048L * 2048, nullptr, 1.0f, 2048);

  // out = context @ w_out^T + b_out   [8192 x 2048] f32
  gemm256<0><<<dim3(8, 32, 1), 512, 0, stream>>>(
      CTX, 2048, 0, Wouth, 2048, 0, out, 2048, 0, b_out, 1.0f, 2048);
}